// Round 11
// baseline (339.091 us; speedup 1.0000x reference)
//
#include <hip/hip_runtime.h>

// GCN 2-layer forward, fp32. Build: 2-pass MSD radix sort by target node
// (coarse 512-node buckets). Aggregate: one wave per node, float4-lane
// gathers, register acc. Round-11: D=8 depth (round-9's 16 outstanding
// loads/wave) at round-10's 0.5 load-inst/edge lane shape — r10 evidence:
// D=4 halved MLP -> latency-bound (VALU 27%). Sort kernel widened to 512
// threads (196 blocks was 25% CU coverage).

#define WAVE 64
#define BN2 512           // nodes per bucket (9 bits local col)
#define NBMAX 256         // max coarse buckets (N <= 131072)
#define CHUNK 8192        // edges per partition block

// ---- bucket count: global histogram of col>>9 ----
__global__ void bucket_count_kernel(const int* __restrict__ col, int* __restrict__ gcnt,
                                    int E, int nb) {
    __shared__ int h[NBMAX];
    for (int i = threadIdx.x; i < nb; i += blockDim.x) h[i] = 0;
    __syncthreads();
    for (int e = blockIdx.x * blockDim.x + threadIdx.x; e < E; e += gridDim.x * blockDim.x)
        atomicAdd(&h[col[e] >> 9], 1);
    __syncthreads();
    for (int i = threadIdx.x; i < nb; i += blockDim.x)
        if (h[i]) atomicAdd(&gcnt[i], h[i]);
}

// ---- exclusive scan of bucket counts -> bptr[nb+1], init gcursor ----
__global__ void bucket_scan_kernel(const int* __restrict__ cnt, int* __restrict__ bptr,
                                   int* __restrict__ gcur, int nb) {
    int lane = threadIdx.x;  // single wave
    int carry = 0;
    for (int base = 0; base < nb; base += WAVE) {
        int i = base + lane;
        int orig = (i < nb) ? cnt[i] : 0;
        int v = orig;
#pragma unroll
        for (int off = 1; off < WAVE; off <<= 1) {
            int t = __shfl_up(v, off, WAVE);
            if (lane >= off) v += t;
        }
        if (i < nb) { bptr[i] = carry + v - orig; gcur[i] = carry + v - orig; }
        carry += __shfl(v, WAVE - 1, WAVE);
    }
    if (lane == 0) bptr[nb] = carry;
}

// ---- pass 1: LDS-binned partition of packed (src<<9 | local_col) ----
__global__ void __launch_bounds__(512)
partition_kernel(const int* __restrict__ row, const int* __restrict__ col,
                 int* __restrict__ gcursor, unsigned* __restrict__ packed,
                 int E, int nb) {
    __shared__ int hist[NBMAX], excl[NBMAX], cursor[NBMAX], baseoff[NBMAX];
    __shared__ unsigned stage[CHUNK];
    int chunk0 = blockIdx.x * CHUNK;
    int cn = E - chunk0; if (cn > CHUNK) cn = CHUNK;
    for (int i = threadIdx.x; i < nb; i += blockDim.x) hist[i] = 0;
    __syncthreads();
    for (int i = threadIdx.x; i < cn; i += blockDim.x)
        atomicAdd(&hist[col[chunk0 + i] >> 9], 1);
    __syncthreads();
    if (threadIdx.x < WAVE) {
        int lane = threadIdx.x, carry = 0;
        for (int base = 0; base < nb; base += WAVE) {
            int i = base + lane;
            int orig = (i < nb) ? hist[i] : 0;
            int v = orig;
#pragma unroll
            for (int off = 1; off < WAVE; off <<= 1) {
                int t = __shfl_up(v, off, WAVE);
                if (lane >= off) v += t;
            }
            if (i < nb) { excl[i] = carry + v - orig; cursor[i] = carry + v - orig; }
            carry += __shfl(v, WAVE - 1, WAVE);
        }
    }
    __syncthreads();
    for (int b = threadIdx.x; b < nb; b += blockDim.x) {
        int c = hist[b];
        baseoff[b] = c ? atomicAdd(&gcursor[b], c) : 0;
    }
    __syncthreads();
    for (int i = threadIdx.x; i < cn; i += blockDim.x) {
        int c = col[chunk0 + i], r = row[chunk0 + i];
        int b = c >> 9;
        int pos = atomicAdd(&cursor[b], 1);
        stage[pos] = ((unsigned)r << 9) | (unsigned)(c & (BN2 - 1));
    }
    __syncthreads();
    int wave = threadIdx.x >> 6, lane = threadIdx.x & 63, nw = blockDim.x >> 6;
    for (int b = wave; b < nb; b += nw) {
        int c = hist[b]; if (!c) continue;
        int s = excl[b], d = baseoff[b];
        for (int k = lane; k < c; k += WAVE) packed[d + k] = stage[s + k];
    }
}

// ---- pass 2: per-bucket sort by local node -> srcs, rowptr, dinv ----
__global__ void __launch_bounds__(512)
sort_kernel(const int* __restrict__ bptr, const unsigned* __restrict__ packed,
            int* __restrict__ srcs, int* __restrict__ rowptr,
            float* __restrict__ dinv, int n, int nb, int E) {
    __shared__ int hist[BN2], excl[BN2], cur[BN2];
    int b = blockIdx.x;
    int start = bptr[b], end = bptr[b + 1];
    for (int i = threadIdx.x; i < BN2; i += blockDim.x) hist[i] = 0;
    __syncthreads();
    for (int k = start + threadIdx.x; k < end; k += blockDim.x)
        atomicAdd(&hist[packed[k] & (BN2 - 1)], 1);
    __syncthreads();
    if (threadIdx.x < WAVE) {
        int lane = threadIdx.x, carry = 0;
#pragma unroll
        for (int base = 0; base < BN2; base += WAVE) {
            int i = base + lane;
            int orig = hist[i];
            int v = orig;
#pragma unroll
            for (int off = 1; off < WAVE; off <<= 1) {
                int t = __shfl_up(v, off, WAVE);
                if (lane >= off) v += t;
            }
            excl[i] = carry + v - orig;
            cur[i]  = carry + v - orig;
            carry += __shfl(v, WAVE - 1, WAVE);
        }
    }
    __syncthreads();
    for (int i = threadIdx.x; i < BN2; i += blockDim.x) {
        int node = b * BN2 + i;
        if (node < n) {
            rowptr[node] = start + excl[i];
            dinv[node]   = hist[i] ? rsqrtf((float)hist[i]) : 0.f;
        }
    }
    if (b == nb - 1 && threadIdx.x == 0) rowptr[n] = E;
    __syncthreads();
    for (int k = start + threadIdx.x; k < end; k += blockDim.x) {
        unsigned p = packed[k];
        int lc = p & (BN2 - 1);
        int pos = atomicAdd(&cur[lc], 1);
        srcs[start + pos] = (int)(p >> 9);
    }
}

// ---- dense: h[n,OUTC] = (x[n,INC] @ W) * dinv[n].
//      Thread = 2 nodes x 4 j. W^T in LDS, stride INC+4 (conflict-free). ----
template <int INC, int OUTC, int JT>
__global__ void __launch_bounds__(256, 4)
dense_kernel(const float* __restrict__ x, const float* __restrict__ W,
             const float* __restrict__ dinv, float* __restrict__ h, int n) {
    const int LSTR = INC + 4;
    const int SP   = 256 / JT;     // node slots (pairs) per block
    const int NT   = SP * 2;       // nodes per block
    __shared__ float Wt[OUTC * LSTR];
    for (int i = threadIdx.x; i < INC * OUTC; i += 256) {
        int k = i / OUTC, j = i % OUTC;
        Wt[j * LSTR + k] = W[i];
    }
    __syncthreads();
    const int jg = threadIdx.x % JT;
    const int sp = threadIdx.x / JT;
    int base = blockIdx.x * NT;
    int n0 = base + sp;
    int n1 = base + sp + SP;
    int n0c = n0 < n ? n0 : n - 1;   // clamp reads, guard writes
    int n1c = n1 < n ? n1 : n - 1;
    const float4* xr0 = (const float4*)(x + (size_t)n0c * INC);
    const float4* xr1 = (const float4*)(x + (size_t)n1c * INC);
    float a[2][4] = {{0.f, 0.f, 0.f, 0.f}, {0.f, 0.f, 0.f, 0.f}};
#pragma unroll 4
    for (int k4 = 0; k4 < INC / 4; ++k4) {
        float4 v0 = xr0[k4];
        float4 v1 = xr1[k4];
#pragma unroll
        for (int u = 0; u < 4; ++u) {
            float4 w = *(const float4*)(Wt + (jg + u * JT) * LSTR + 4 * k4);
            a[0][u] = fmaf(v0.x, w.x, fmaf(v0.y, w.y, fmaf(v0.z, w.z, fmaf(v0.w, w.w, a[0][u]))));
            a[1][u] = fmaf(v1.x, w.x, fmaf(v1.y, w.y, fmaf(v1.z, w.z, fmaf(v1.w, w.w, a[1][u]))));
        }
    }
    if (n0 < n) {
        float d = dinv[n0];
        float* hr = h + (size_t)n0 * OUTC;
#pragma unroll
        for (int u = 0; u < 4; ++u) hr[jg + u * JT] = a[0][u] * d;
    }
    if (n1 < n) {
        float d = dinv[n1];
        float* hr = h + (size_t)n1 * OUTC;
#pragma unroll
        for (int u = 0; u < 4; ++u) hr[jg + u * JT] = a[1][u] * d;
    }
}

// ---- aggregate: one wave per node; C/4 lanes x float4 per edge-row;
//      EPW = 256/C edges in flight; predicated 8-deep batches (16
//      outstanding loads/wave — the measured MLP sweet spot). ----
template <int C, bool RELU>
__global__ void csr_agg_kernel(const int* __restrict__ rowptr, const int* __restrict__ srcs,
                               const float* __restrict__ dinv, const float* __restrict__ hs,
                               const float* __restrict__ bias, float* __restrict__ out, int n) {
    const int EPW = 256 / C;   // edges in flight per wave (C=32:8, C=16:16)
    const int D   = 8;         // batch depth
    int node = (int)((blockIdx.x * (unsigned)blockDim.x + threadIdx.x) >> 6);
    int lane = threadIdx.x & 63;
    int eo = lane & (EPW - 1);   // consecutive lanes -> consecutive srcs
    int jq = lane / EPW;         // float4 slot within the row
    if (node >= n) return;
    int start = rowptr[node], end = rowptr[node + 1];
    float4 acc = {0.f, 0.f, 0.f, 0.f};
    for (int k = start + eo; k < end; k += D * EPW) {
        int   s[D];
        float m[D];
#pragma unroll
        for (int u = 0; u < D; ++u) {
            int t = k + u * EPW;
            int cl = t < end ? t : end - 1;
            s[u] = srcs[cl];
            m[u] = t < end ? 1.f : 0.f;
        }
        float4 hv[D];
#pragma unroll
        for (int u = 0; u < D; ++u)
            hv[u] = *(const float4*)(hs + (size_t)s[u] * C + jq * 4);
#pragma unroll
        for (int u = 0; u < D; ++u) {
            acc.x = fmaf(m[u], hv[u].x, acc.x);
            acc.y = fmaf(m[u], hv[u].y, acc.y);
            acc.z = fmaf(m[u], hv[u].z, acc.z);
            acc.w = fmaf(m[u], hv[u].w, acc.w);
        }
    }
#pragma unroll
    for (int off = 1; off < EPW; off <<= 1) {
        acc.x += __shfl_xor(acc.x, off, WAVE);
        acc.y += __shfl_xor(acc.y, off, WAVE);
        acc.z += __shfl_xor(acc.z, off, WAVE);
        acc.w += __shfl_xor(acc.w, off, WAVE);
    }
    if (eo == 0) {
        float d = dinv[node];
        float4 b = *(const float4*)(bias + jq * 4);
        float4 v;
        v.x = acc.x * d + b.x;
        v.y = acc.y * d + b.y;
        v.z = acc.z * d + b.z;
        v.w = acc.w * d + b.w;
        if (RELU) {
            v.x = v.x > 0.f ? v.x : 0.f;
            v.y = v.y > 0.f ? v.y : 0.f;
            v.z = v.z > 0.f ? v.z : 0.f;
            v.w = v.w > 0.f ? v.w : 0.f;
        }
        *(float4*)(out + (size_t)node * C + jq * 4) = v;
    }
}

__global__ void tail_kernel(float* __restrict__ out, int idx) {
    if (blockIdx.x == 0 && threadIdx.x == 0) out[idx] = 0.f;
}

extern "C" void kernel_launch(void* const* d_in, const int* in_sizes, int n_in,
                              void* d_out, int out_size, void* d_ws, size_t ws_size,
                              hipStream_t stream) {
    const float* x  = (const float*)d_in[0];
    const int*   ei = (const int*)d_in[1];    // harness converts int64 -> int32
    const float* W1 = (const float*)d_in[2];
    const float* b1 = (const float*)d_in[3];
    const float* W2 = (const float*)d_in[4];
    const float* b2 = (const float*)d_in[5];

    const int IN_C = 128, HID = 32, OC = 16;
    const int N = in_sizes[0] / IN_C;       // 100000
    const int E = in_sizes[1] / 2;          // 3200000
    const int* row = ei;
    const int* col = ei + E;
    const int NB = (N + BN2 - 1) / BN2;     // 196 coarse buckets

    char* base = (char*)d_ws;
    size_t off = 0;
    auto carve = [&](size_t bytes) -> char* {
        char* p = base + off;
        off = (off + bytes + 255) & ~(size_t)255;
        return p;
    };
    int*      gcnt   = (int*)     carve((size_t)NB * 4);
    int*      bptr   = (int*)     carve((size_t)(NB + 1) * 4);
    int*      gcur   = (int*)     carve((size_t)NB * 4);
    int*      rowptr = (int*)     carve((size_t)(N + 1) * 4);
    float*    dinv   = (float*)   carve((size_t)N * 4);
    unsigned* packed = (unsigned*)carve((size_t)E * 4);
    int*      srcs   = (int*)     carve((size_t)E * 4);
    float*    bufA   = (float*)   carve((size_t)N * HID * 4);  // h1', then h2'
    float*    bufB   = (float*)   carve((size_t)N * HID * 4);  // relu(agg1)
    (void)ws_size; (void)n_in;

    float* outp = (float*)d_out;

    // build: 2-pass coarse radix sort by target node + rowptr + dinv
    hipMemsetAsync(gcnt, 0, (size_t)NB * 4, stream);
    bucket_count_kernel<<<512, 256, 0, stream>>>(col, gcnt, E, NB);
    bucket_scan_kernel<<<1, 64, 0, stream>>>(gcnt, bptr, gcur, NB);
    partition_kernel<<<(E + CHUNK - 1) / CHUNK, 512, 0, stream>>>(row, col, gcur, packed, E, NB);
    sort_kernel<<<NB, 512, 0, stream>>>(bptr, packed, srcs, rowptr, dinv, N, NB, E);

    // layer 1: h1' = (x@W1)*dinv ; bufB = relu(dinv*agg(h1') + b1)
    {
        const int NT = (256 / 8) * 2;  // 64 nodes per block
        dense_kernel<128, 32, 8><<<(N + NT - 1) / NT, 256, 0, stream>>>(x, W1, dinv, bufA, N);
        int nppb = 256 / WAVE;         // 4 nodes per block
        csr_agg_kernel<32, true><<<(N + nppb - 1) / nppb, 256, 0, stream>>>(
            rowptr, srcs, dinv, bufA, b1, bufB, N);
    }
    // layer 2: h2' = (bufB@W2)*dinv ; out = dinv*agg(h2') + b2
    {
        const int NT = (256 / 4) * 2;  // 128 nodes per block
        dense_kernel<32, 16, 4><<<(N + NT - 1) / NT, 256, 0, stream>>>(bufB, W2, dinv, bufA, N);
        int nppb = 256 / WAVE;
        csr_agg_kernel<16, false><<<(N + nppb - 1) / nppb, 256, 0, stream>>>(
            rowptr, srcs, dinv, bufA, b2, outp, N);
    }
    if (out_size > N * OC)
        tail_kernel<<<1, 64, 0, stream>>>(outp, N * OC);
}

// Round 12
// 299.246 us; speedup vs baseline: 1.1331x; 1.1331x over previous
//
#include <hip/hip_runtime.h>

// GCN 2-layer forward, fp32 in/out, fp16 gather tables. Build: 2-pass MSD
// radix sort by target node. Aggregate: one wave per node, scalar gathers
// (round-11 evidence: >2 unique rows per gather inst regresses — lane map
// keeps all C lanes on one contiguous row), predicated D=8, register acc.
// Round-12: h' tables stored fp16 (6.4 MB, 1 line/row) — agg was L2-miss
// bound (FETCH 154 MB vs 12.8 MB table vs 4 MiB/XCD L2). fp32 accumulate
// via v_fma_mix; error budget ~3e-4 << 4e-3 threshold.

#define WAVE 64
#define BN2 512           // nodes per bucket (9 bits local col)
#define NBMAX 256         // max coarse buckets (N <= 131072)
#define CHUNK 8192        // edges per partition block

typedef _Float16 f16;

// ---- bucket count: global histogram of col>>9 ----
__global__ void bucket_count_kernel(const int* __restrict__ col, int* __restrict__ gcnt,
                                    int E, int nb) {
    __shared__ int h[NBMAX];
    for (int i = threadIdx.x; i < nb; i += blockDim.x) h[i] = 0;
    __syncthreads();
    for (int e = blockIdx.x * blockDim.x + threadIdx.x; e < E; e += gridDim.x * blockDim.x)
        atomicAdd(&h[col[e] >> 9], 1);
    __syncthreads();
    for (int i = threadIdx.x; i < nb; i += blockDim.x)
        if (h[i]) atomicAdd(&gcnt[i], h[i]);
}

// ---- exclusive scan of bucket counts -> bptr[nb+1], init gcursor ----
__global__ void bucket_scan_kernel(const int* __restrict__ cnt, int* __restrict__ bptr,
                                   int* __restrict__ gcur, int nb) {
    int lane = threadIdx.x;  // single wave
    int carry = 0;
    for (int base = 0; base < nb; base += WAVE) {
        int i = base + lane;
        int orig = (i < nb) ? cnt[i] : 0;
        int v = orig;
#pragma unroll
        for (int off = 1; off < WAVE; off <<= 1) {
            int t = __shfl_up(v, off, WAVE);
            if (lane >= off) v += t;
        }
        if (i < nb) { bptr[i] = carry + v - orig; gcur[i] = carry + v - orig; }
        carry += __shfl(v, WAVE - 1, WAVE);
    }
    if (lane == 0) bptr[nb] = carry;
}

// ---- pass 1: LDS-binned partition of packed (src<<9 | local_col) ----
__global__ void __launch_bounds__(512)
partition_kernel(const int* __restrict__ row, const int* __restrict__ col,
                 int* __restrict__ gcursor, unsigned* __restrict__ packed,
                 int E, int nb) {
    __shared__ int hist[NBMAX], excl[NBMAX], cursor[NBMAX], baseoff[NBMAX];
    __shared__ unsigned stage[CHUNK];
    int chunk0 = blockIdx.x * CHUNK;
    int cn = E - chunk0; if (cn > CHUNK) cn = CHUNK;
    for (int i = threadIdx.x; i < nb; i += blockDim.x) hist[i] = 0;
    __syncthreads();
    for (int i = threadIdx.x; i < cn; i += blockDim.x)
        atomicAdd(&hist[col[chunk0 + i] >> 9], 1);
    __syncthreads();
    if (threadIdx.x < WAVE) {
        int lane = threadIdx.x, carry = 0;
        for (int base = 0; base < nb; base += WAVE) {
            int i = base + lane;
            int orig = (i < nb) ? hist[i] : 0;
            int v = orig;
#pragma unroll
            for (int off = 1; off < WAVE; off <<= 1) {
                int t = __shfl_up(v, off, WAVE);
                if (lane >= off) v += t;
            }
            if (i < nb) { excl[i] = carry + v - orig; cursor[i] = carry + v - orig; }
            carry += __shfl(v, WAVE - 1, WAVE);
        }
    }
    __syncthreads();
    for (int b = threadIdx.x; b < nb; b += blockDim.x) {
        int c = hist[b];
        baseoff[b] = c ? atomicAdd(&gcursor[b], c) : 0;
    }
    __syncthreads();
    for (int i = threadIdx.x; i < cn; i += blockDim.x) {
        int c = col[chunk0 + i], r = row[chunk0 + i];
        int b = c >> 9;
        int pos = atomicAdd(&cursor[b], 1);
        stage[pos] = ((unsigned)r << 9) | (unsigned)(c & (BN2 - 1));
    }
    __syncthreads();
    int wave = threadIdx.x >> 6, lane = threadIdx.x & 63, nw = blockDim.x >> 6;
    for (int b = wave; b < nb; b += nw) {
        int c = hist[b]; if (!c) continue;
        int s = excl[b], d = baseoff[b];
        for (int k = lane; k < c; k += WAVE) packed[d + k] = stage[s + k];
    }
}

// ---- pass 2: per-bucket sort by local node -> srcs, rowptr, dinv ----
__global__ void __launch_bounds__(512)
sort_kernel(const int* __restrict__ bptr, const unsigned* __restrict__ packed,
            int* __restrict__ srcs, int* __restrict__ rowptr,
            float* __restrict__ dinv, int n, int nb, int E) {
    __shared__ int hist[BN2], excl[BN2], cur[BN2];
    int b = blockIdx.x;
    int start = bptr[b], end = bptr[b + 1];
    for (int i = threadIdx.x; i < BN2; i += blockDim.x) hist[i] = 0;
    __syncthreads();
    for (int k = start + threadIdx.x; k < end; k += blockDim.x)
        atomicAdd(&hist[packed[k] & (BN2 - 1)], 1);
    __syncthreads();
    if (threadIdx.x < WAVE) {
        int lane = threadIdx.x, carry = 0;
#pragma unroll
        for (int base = 0; base < BN2; base += WAVE) {
            int i = base + lane;
            int orig = hist[i];
            int v = orig;
#pragma unroll
            for (int off = 1; off < WAVE; off <<= 1) {
                int t = __shfl_up(v, off, WAVE);
                if (lane >= off) v += t;
            }
            excl[i] = carry + v - orig;
            cur[i]  = carry + v - orig;
            carry += __shfl(v, WAVE - 1, WAVE);
        }
    }
    __syncthreads();
    for (int i = threadIdx.x; i < BN2; i += blockDim.x) {
        int node = b * BN2 + i;
        if (node < n) {
            rowptr[node] = start + excl[i];
            dinv[node]   = hist[i] ? rsqrtf((float)hist[i]) : 0.f;
        }
    }
    if (b == nb - 1 && threadIdx.x == 0) rowptr[n] = E;
    __syncthreads();
    for (int k = start + threadIdx.x; k < end; k += blockDim.x) {
        unsigned p = packed[k];
        int lc = p & (BN2 - 1);
        int pos = atomicAdd(&cur[lc], 1);
        srcs[start + pos] = (int)(p >> 9);
    }
}

// ---- dense: h[n,OUTC] = fp16( (x[n,INC] @ W) * dinv[n] ).
//      Thread = 2 nodes x 4 j. W^T in LDS, stride INC+4 (conflict-free). ----
template <int INC, int OUTC, int JT>
__global__ void __launch_bounds__(256, 4)
dense_kernel(const float* __restrict__ x, const float* __restrict__ W,
             const float* __restrict__ dinv, f16* __restrict__ h, int n) {
    const int LSTR = INC + 4;
    const int SP   = 256 / JT;     // node slots (pairs) per block
    const int NT   = SP * 2;       // nodes per block
    __shared__ float Wt[OUTC * LSTR];
    for (int i = threadIdx.x; i < INC * OUTC; i += 256) {
        int k = i / OUTC, j = i % OUTC;
        Wt[j * LSTR + k] = W[i];
    }
    __syncthreads();
    const int jg = threadIdx.x % JT;
    const int sp = threadIdx.x / JT;
    int base = blockIdx.x * NT;
    int n0 = base + sp;
    int n1 = base + sp + SP;
    int n0c = n0 < n ? n0 : n - 1;   // clamp reads, guard writes
    int n1c = n1 < n ? n1 : n - 1;
    const float4* xr0 = (const float4*)(x + (size_t)n0c * INC);
    const float4* xr1 = (const float4*)(x + (size_t)n1c * INC);
    float a[2][4] = {{0.f, 0.f, 0.f, 0.f}, {0.f, 0.f, 0.f, 0.f}};
#pragma unroll 4
    for (int k4 = 0; k4 < INC / 4; ++k4) {
        float4 v0 = xr0[k4];
        float4 v1 = xr1[k4];
#pragma unroll
        for (int u = 0; u < 4; ++u) {
            float4 w = *(const float4*)(Wt + (jg + u * JT) * LSTR + 4 * k4);
            a[0][u] = fmaf(v0.x, w.x, fmaf(v0.y, w.y, fmaf(v0.z, w.z, fmaf(v0.w, w.w, a[0][u]))));
            a[1][u] = fmaf(v1.x, w.x, fmaf(v1.y, w.y, fmaf(v1.z, w.z, fmaf(v1.w, w.w, a[1][u]))));
        }
    }
    if (n0 < n) {
        float d = dinv[n0];
        f16* hr = h + (size_t)n0 * OUTC;
#pragma unroll
        for (int u = 0; u < 4; ++u) hr[jg + u * JT] = (f16)(a[0][u] * d);
    }
    if (n1 < n) {
        float d = dinv[n1];
        f16* hr = h + (size_t)n1 * OUTC;
#pragma unroll
        for (int u = 0; u < 4; ++u) hr[jg + u * JT] = (f16)(a[1][u] * d);
    }
}

// ---- aggregate: one wave per node; C lanes cover one contiguous fp16 row
//      (64 B = 1 line at C=32); EPW=64/C edges in flight; predicated D=8. ----
template <int C, bool RELU>
__global__ void csr_agg_kernel(const int* __restrict__ rowptr, const int* __restrict__ srcs,
                               const float* __restrict__ dinv, const f16* __restrict__ hs,
                               const float* __restrict__ bias, float* __restrict__ out, int n) {
    const int EPW = WAVE / C;  // edges in flight per wave-step
    const int D   = 8;         // batch depth
    int node = (int)((blockIdx.x * (unsigned)blockDim.x + threadIdx.x) >> 6);
    int lane = threadIdx.x & 63;
    int j  = lane & (C - 1);
    int eo = lane / C;
    if (node >= n) return;
    int start = rowptr[node], end = rowptr[node + 1];
    float acc = 0.f;
    for (int k = start + eo; k < end; k += D * EPW) {
        int   s[D];
        float m[D];
#pragma unroll
        for (int u = 0; u < D; ++u) {
            int t = k + u * EPW;
            int cl = t < end ? t : end - 1;
            s[u] = srcs[cl];
            m[u] = t < end ? 1.f : 0.f;
        }
        f16 hv[D];
#pragma unroll
        for (int u = 0; u < D; ++u)
            hv[u] = hs[(size_t)s[u] * C + j];
#pragma unroll
        for (int u = 0; u < D; ++u)
            acc = fmaf(m[u], (float)hv[u], acc);   // v_fma_mix
    }
#pragma unroll
    for (int off = C; off < WAVE; off <<= 1)
        acc += __shfl_xor(acc, off, WAVE);
    if (eo == 0) {
        float v = acc * dinv[node] + bias[j];
        if (RELU) v = v > 0.f ? v : 0.f;
        out[(size_t)node * C + j] = v;
    }
}

__global__ void tail_kernel(float* __restrict__ out, int idx) {
    if (blockIdx.x == 0 && threadIdx.x == 0) out[idx] = 0.f;
}

extern "C" void kernel_launch(void* const* d_in, const int* in_sizes, int n_in,
                              void* d_out, int out_size, void* d_ws, size_t ws_size,
                              hipStream_t stream) {
    const float* x  = (const float*)d_in[0];
    const int*   ei = (const int*)d_in[1];    // harness converts int64 -> int32
    const float* W1 = (const float*)d_in[2];
    const float* b1 = (const float*)d_in[3];
    const float* W2 = (const float*)d_in[4];
    const float* b2 = (const float*)d_in[5];

    const int IN_C = 128, HID = 32, OC = 16;
    const int N = in_sizes[0] / IN_C;       // 100000
    const int E = in_sizes[1] / 2;          // 3200000
    const int* row = ei;
    const int* col = ei + E;
    const int NB = (N + BN2 - 1) / BN2;     // 196 coarse buckets

    char* base = (char*)d_ws;
    size_t off = 0;
    auto carve = [&](size_t bytes) -> char* {
        char* p = base + off;
        off = (off + bytes + 255) & ~(size_t)255;
        return p;
    };
    int*      gcnt   = (int*)     carve((size_t)NB * 4);
    int*      bptr   = (int*)     carve((size_t)(NB + 1) * 4);
    int*      gcur   = (int*)     carve((size_t)NB * 4);
    int*      rowptr = (int*)     carve((size_t)(N + 1) * 4);
    float*    dinv   = (float*)   carve((size_t)N * 4);
    unsigned* packed = (unsigned*)carve((size_t)E * 4);
    int*      srcs   = (int*)     carve((size_t)E * 4);
    f16*      hA     = (f16*)     carve((size_t)N * HID * 2);  // h1' then h2' (fp16)
    float*    bufB   = (float*)   carve((size_t)N * HID * 4);  // relu(agg1), fp32
    (void)ws_size; (void)n_in;

    float* outp = (float*)d_out;

    // build: 2-pass coarse radix sort by target node + rowptr + dinv
    hipMemsetAsync(gcnt, 0, (size_t)NB * 4, stream);
    bucket_count_kernel<<<512, 256, 0, stream>>>(col, gcnt, E, NB);
    bucket_scan_kernel<<<1, 64, 0, stream>>>(gcnt, bptr, gcur, NB);
    partition_kernel<<<(E + CHUNK - 1) / CHUNK, 512, 0, stream>>>(row, col, gcur, packed, E, NB);
    sort_kernel<<<NB, 512, 0, stream>>>(bptr, packed, srcs, rowptr, dinv, N, NB, E);

    // layer 1: h1' = fp16((x@W1)*dinv) ; bufB = relu(dinv*agg(h1') + b1)
    {
        const int NT = (256 / 8) * 2;  // 64 nodes per block
        dense_kernel<128, 32, 8><<<(N + NT - 1) / NT, 256, 0, stream>>>(x, W1, dinv, hA, N);
        int nppb = 256 / WAVE;         // 4 nodes per block
        csr_agg_kernel<32, true><<<(N + nppb - 1) / nppb, 256, 0, stream>>>(
            rowptr, srcs, dinv, hA, b1, bufB, N);
    }
    // layer 2: h2' = fp16((bufB@W2)*dinv) ; out = dinv*agg(h2') + b2
    {
        const int NT = (256 / 4) * 2;  // 128 nodes per block
        dense_kernel<32, 16, 4><<<(N + NT - 1) / NT, 256, 0, stream>>>(bufB, W2, dinv, hA, N);
        int nppb = 256 / WAVE;
        csr_agg_kernel<16, false><<<(N + nppb - 1) / nppb, 256, 0, stream>>>(
            rowptr, srcs, dinv, hA, b2, outp, N);
    }
    if (out_size > N * OC)
        tail_kernel<<<1, 64, 0, stream>>>(outp, N * OC);
}